// Round 7
// baseline (429.660 us; speedup 1.0000x reference)
//
#include <hip/hip_runtime.h>

// SigWassersteinMetric: depth-4 path signature, C=10, T=256.
//   original: (4096, 256, 10) f32; generated: (1024, 256, 10) f32; sample_idx: (1024,)
//
// ROUND-21: R17 hot loop EXACTLY (best accum: 193us), dispatch-count 4 -> 2.
//   - R18/R19/R20 all FAILED to beat R17's loop by re-balancing LDS<->VALU:
//     every pipe-migration pays a conversion tax (movs/serial chains) that
//     eats the modeled gain. R17 = local optimum for the loop.
//   - Ledger: total 283 = accum 193 + sum ~18 + sumsq ~3 + memset ~2 +
//     ~65us of per-dispatch fixed cost (launch + dependent-grid drain) x4.
//     This round attacks the 65us:
//       * memset dropped -- accum block 0 zero-inits accvec+counter.
//       * sumsq fused into sig_sum via counter/lastflag (last of 1408 blocks
//         re-reads the 44KB accvec from L2 and writes the norm).
//     2 dispatches total. Prediction: accum unchanged ~193, total ~245-260.
//
// Horner-factored Chen step (verified rounds 2/4-13):
//   A2 = S2 + (S1 + v/4) (x) v/3 ;  B2 = S2 + (S1 + v/3) (x) v/2
//   A3 = S3 + A2 (x) v/2 ;  S4' = S4 + A3 (x) v ;  S3' = S3 + B2 (x) v
//   S2' = S2 + (S1 + v/2) (x) v ;  S1 closed-form in epilogue.
#define T_LEN 256
#define C_DIM 10
#define NSTEP 255
#define BSZ   1024
#define NPAIR 1024
#define D1 10
#define D2 100
#define D3 1000
#define DTOT 11110
#define PATH_ELEMS (T_LEN * C_DIM)   // 2560
#define DX_ELEMS (NSTEP * C_DIM)     // 2550
#define DXROW 12                     // padded dx row stride (48 B, 16B-aligned)

typedef float f32x2 __attribute__((ext_vector_type(2)));
typedef float f32x4 __attribute__((ext_vector_type(4)));

// d += bcast(a.lo) * b
#define PK_FMA_B0(d, a, b) \
    asm("v_pk_fma_f32 %0, %1, %2, %0 op_sel:[0,0,0] op_sel_hi:[0,1,1]" \
        : "+v"(d) : "v"(a), "v"(b))
// d += bcast(a.hi) * b
#define PK_FMA_B1(d, a, b) \
    asm("v_pk_fma_f32 %0, %1, %2, %0 op_sel:[1,0,0] op_sel_hi:[1,1,1]" \
        : "+v"(d) : "v"(a), "v"(b))
// d = bcast(a.lo) * b + c
#define PK_FMA_B0N(d, a, b, c) \
    asm("v_pk_fma_f32 %0, %1, %2, %3 op_sel:[0,0,0] op_sel_hi:[0,1,1]" \
        : "=v"(d) : "v"(a), "v"(b), "v"(c))
// d = bcast(a.hi) * b + c
#define PK_FMA_B1N(d, a, b, c) \
    asm("v_pk_fma_f32 %0, %1, %2, %3 op_sel:[1,0,0] op_sel_hi:[1,1,1]" \
        : "=v"(d) : "v"(a), "v"(b), "v"(c))
// d = a * bcast(b.lo) + c   (src1 broadcast)
#define PK_FMA_S1B0N(d, a, b, c) \
    asm("v_pk_fma_f32 %0, %1, %2, %3 op_sel:[0,0,0] op_sel_hi:[1,0,1]" \
        : "=v"(d) : "v"(a), "v"(b), "v"(c))
// d = a * bcast(b.hi) + c
#define PK_FMA_S1B1N(d, a, b, c) \
    asm("v_pk_fma_f32 %0, %1, %2, %3 op_sel:[0,1,0] op_sel_hi:[1,1,1]" \
        : "=v"(d) : "v"(a), "v"(b), "v"(c))
// d += a * bcast(b.lo)
#define PK_FMA_S1B0(d, a, b) \
    asm("v_pk_fma_f32 %0, %1, %2, %0 op_sel:[0,0,0] op_sel_hi:[1,0,1]" \
        : "+v"(d) : "v"(a), "v"(b))
// d += a * bcast(b.hi)
#define PK_FMA_S1B1(d, a, b) \
    asm("v_pk_fma_f32 %0, %1, %2, %0 op_sel:[0,1,0] op_sel_hi:[1,1,1]" \
        : "+v"(d) : "v"(a), "v"(b))
// d = a * 0.5 (both halves)
#define PK_MUL_HALF(d, a) \
    asm("v_pk_mul_f32 %0, %1, 0.5 op_sel:[0,0] op_sel_hi:[1,0]" \
        : "=v"(d) : "v"(a))

__global__ __launch_bounds__(256)
void sig_accum_kernel(
    const float* __restrict__ original,
    const float* __restrict__ generated,
    const int* __restrict__ sample_idx,
    float* __restrict__ ws,
    float* __restrict__ accinit,   // non-null: block 0 zeroes DTOT+2 floats
    int nrep, int store_mode)
{
    const int tid  = threadIdx.x;
    const int bp   = blockIdx.x;         // 0 .. 2*NPAIR-1
    const int b    = bp >> 1;            // pair index
    const int pass = bp & 1;             // 0 = generated (-), 1 = original (+)
    const float sgn = pass ? 1.0f : -1.0f;

    __shared__ __align__(16) float s_dx[NSTEP * DXROW];  // 12240 B

    if (accinit != nullptr && bp == 0) {
        for (int i = tid; i < DTOT + 2; i += 256) accinit[i] = 0.0f;
    }

    const float* path = pass
        ? original + (size_t)sample_idx[b] * PATH_ELEMS
        : generated + (size_t)b * PATH_ELEMS;

    for (int idx = tid; idx < DX_ELEMS; idx += 256) {
        int t = idx / C_DIM, c = idx - t * C_DIM;
        s_dx[t * DXROW + c] = path[idx + C_DIM] - path[idx];
    }
    __syncthreads();

    const int mbase = 2 * tid;               // valid tid<250
    const int k0  = mbase / 100;             // 0..4
    const int ij0 = mbase - k0 * 100;        // even
    const int ia  = ij0 / 10;
    const int j0  = ij0 - ia * 10;           // even -> (j0, j0+1) same decade

    float s1a = 0.0f;
    f32x2 s2p = {0.0f, 0.0f};                 // (q0, q1)
    f32x2 s3p[2] = {{0.0f, 0.0f}, {0.0f, 0.0f}};  // [0]=(q0,q1)@k0, [1]=@k1
    f32x2 acc2[4][5];                         // [0]=q0k0 [1]=q1k0 [2]=q0k1 [3]=q1k1
    #pragma unroll
    for (int r = 0; r < 4; ++r)
        #pragma unroll
        for (int i = 0; i < 5; ++i) acc2[r][i] = (f32x2){0.0f, 0.0f};

    if (tid < 250) {
        const float* vrow = s_dx;
        #pragma unroll 2
        for (int t = 0; t < NSTEP; ++t, vrow += DXROW) {
            const f32x4 va = *(const f32x4*)(vrow);        // v0..v3 (uniform)
            const f32x4 vb = *(const f32x4*)(vrow + 4);    // v4..v7 (uniform)
            const f32x2 vc = *(const f32x2*)(vrow + 8);    // v8,v9  (uniform)
            const f32x2 vjp = *(const f32x2*)(vrow + j0);  // vj for q0,q1
            const float via = vrow[ia];
            f32x2 vkp;
            vkp.x = vrow[k0];
            vkp.y = vrow[k0 + 5];

            const f32x2 vv2[5] = {va.xy, va.zw, vb.xy, vb.zw, vc};

            // scalar prefix terms
            const float t3  = fmaf(via, 0.5f, s1a);
            const float t1b = fmaf(via, 0.25f, s1a) * (1.0f / 3.0f);
            const float t2b = fmaf(via, (1.0f / 3.0f), s1a) * 0.5f;
            f32x2 pA; pA.x = t1b; pA.y = t2b;
            f32x2 pT; pT.x = t3;  pT.y = t3;

            f32x2 vkhp;                       // (vk0*0.5, vk1*0.5)
            PK_MUL_HALF(vkhp, vkp);

            // level 2 (q-pairs)
            f32x2 a2p, b2p;
            PK_FMA_B0N(a2p, pA, vjp, s2p);    // a2_q = t1b*vj_q + s2_q
            PK_FMA_B1N(b2p, pA, vjp, s2p);    // b2_q = t2b*vj_q + s2_q
            PK_FMA_B0(s2p, pT, vjp);          // s2_q += t3*vj_q

            // level 3 (q-pairs, k-channel broadcast from vkp/vkhp halves)
            f32x2 a3xp, a3yp;
            PK_FMA_S1B0N(a3xp, a2p, vkhp, s3p[0]);  // a3_q@k0
            PK_FMA_S1B1N(a3yp, a2p, vkhp, s3p[1]);  // a3_q@k1
            PK_FMA_S1B0(s3p[0], b2p, vkp);          // s3_q@k0 += b2_q*vk0
            PK_FMA_S1B1(s3p[1], b2p, vkp);          // s3_q@k1 += b2_q*vk1

            // level 4: 20 pk-FMAs (a3 broadcast from pair halves)
            #pragma unroll
            for (int i = 0; i < 5; ++i) {
                PK_FMA_B0(acc2[0][i], a3xp, vv2[i]);
                PK_FMA_B1(acc2[1][i], a3xp, vv2[i]);
                PK_FMA_B0(acc2[2][i], a3yp, vv2[i]);
                PK_FMA_B1(acc2[3][i], a3yp, vv2[i]);
            }
            s1a += via;
        }
    }

    // ---- Epilogue: signed single-path row ----
    if (store_mode) {
        float* row = ws + (size_t)bp * DTOT;
        if (tid < D1)
            row[tid] = sgn * (path[(T_LEN - 1) * C_DIM + tid] - path[tid]);
        if (tid < 50) {       // k0 == 0 threads own ij0 = 2*tid
            row[D1 + ij0]     = sgn * s2p[0];
            row[D1 + ij0 + 1] = sgn * s2p[1];
        }
        if (tid < 250) {
            #pragma unroll
            for (int ch = 0; ch < 2; ++ch) {          // ch=0 -> k0, ch=1 -> k0+5
                const int kk = k0 + 5 * ch;
                #pragma unroll
                for (int q = 0; q < 2; ++q) {
                    const int idx3 = (ij0 + q) * 10 + kk;
                    row[D1 + D2 + idx3] = sgn * s3p[ch][q];
                    float* p4 = row + D1 + D2 + D3 + (size_t)idx3 * 10;
                    #pragma unroll
                    for (int i = 0; i < 5; ++i)
                        *(f32x2*)&p4[2 * i] = sgn * acc2[ch * 2 + q][i];
                }
            }
        }
    } else {
        float* base = ws + (size_t)(b % nrep) * DTOT;
        if (tid < D1)
            atomicAdd(&base[tid],
                      sgn * (path[(T_LEN - 1) * C_DIM + tid] - path[tid]));
        if (tid < 50) {
            atomicAdd(&base[D1 + ij0],     sgn * s2p[0]);
            atomicAdd(&base[D1 + ij0 + 1], sgn * s2p[1]);
        }
        if (tid < 250) {
            #pragma unroll
            for (int ch = 0; ch < 2; ++ch) {
                const int kk = k0 + 5 * ch;
                #pragma unroll
                for (int q = 0; q < 2; ++q) {
                    const int idx3 = (ij0 + q) * 10 + kk;
                    atomicAdd(&base[D1 + D2 + idx3], sgn * s3p[ch][q]);
                    #pragma unroll
                    for (int l = 0; l < 10; ++l)
                        atomicAdd(&base[D1 + D2 + D3 + idx3 * 10 + l],
                                  sgn * acc2[ch * 2 + q][l >> 1][l & 1]);
                }
            }
        }
    }
}

// Fused stage 1+2: each block sums 32 rows for a float2 d-tile (coalesced)
// into accvec via atomics; the LAST block re-reads accvec (L2-hot) and
// writes the final norm. Grid: (ceil(5555/256), nrows/32).
__global__ __launch_bounds__(256) void sig_sum_kernel(
    const float* __restrict__ ws, float* __restrict__ accvec,
    unsigned int* __restrict__ counter, float* __restrict__ out, int nblocks)
{
    const int d2 = blockIdx.x * 256 + threadIdx.x;   // DTOT/2 = 5555
    if (d2 < DTOT / 2) {
        const float* p = ws + (size_t)(blockIdx.y * 32) * DTOT + 2 * d2;
        float sx = 0.0f, sy = 0.0f;
        #pragma unroll
        for (int r = 0; r < 32; ++r) {
            const float2 v = *(const float2*)(p + (size_t)r * DTOT);
            sx += v.x; sy += v.y;
        }
        atomicAdd(&accvec[2 * d2], sx);
        atomicAdd(&accvec[2 * d2 + 1], sy);
    }

    __shared__ unsigned int lastflag;
    __threadfence();
    __syncthreads();
    if (threadIdx.x == 0)
        lastflag = (atomicAdd(counter, 1u) == (unsigned int)(nblocks - 1));
    __syncthreads();
    if (!lastflag) return;
    __threadfence();

    float s = 0.0f;
    for (int d = (int)threadIdx.x; d < DTOT; d += 256) {
        const float v = accvec[d];
        s = fmaf(v, v, s);
    }
    for (int off = 32; off > 0; off >>= 1) s += __shfl_down(s, off, 64);
    __shared__ float red[4];
    if ((threadIdx.x & 63) == 0) red[threadIdx.x >> 6] = s;
    __syncthreads();
    if (threadIdx.x == 0)
        out[0] = sqrtf(red[0] + red[1] + red[2] + red[3]) * (1.0f / (float)BSZ);
}

// Fallback reduce for small-ws atomic-replica modes.
__global__ __launch_bounds__(256) void sig_reduce_kernel(
    const float* __restrict__ ws, int nrows, float* __restrict__ sumsq,
    unsigned int* __restrict__ counter, float* __restrict__ out, int nblocks)
{
    const int d = blockIdx.x * 256 + threadIdx.x;
    float s = 0.0f;
    if (d < DTOT) {
        for (int r = 0; r < nrows; ++r) s += ws[(size_t)r * DTOT + d];
        s = s * s;
    }
    for (int off = 32; off > 0; off >>= 1) s += __shfl_down(s, off, 64);
    __shared__ float red[4];
    __shared__ unsigned int lastflag;
    if ((threadIdx.x & 63) == 0) red[threadIdx.x >> 6] = s;
    __syncthreads();
    if (threadIdx.x == 0) {
        atomicAdd(sumsq, red[0] + red[1] + red[2] + red[3]);
        __threadfence();
        lastflag = (atomicAdd(counter, 1u) == (unsigned int)(nblocks - 1));
    }
    __syncthreads();
    if (threadIdx.x == 0 && lastflag) {
        __threadfence();
        out[0] = sqrtf(*(volatile float*)sumsq) * (1.0f / (float)BSZ);
    }
}

extern "C" void kernel_launch(void* const* d_in, const int* in_sizes, int n_in,
                              void* d_out, int out_size, void* d_ws, size_t ws_size,
                              hipStream_t stream) {
    const float* original   = (const float*)d_in[0];
    const float* generated  = (const float*)d_in[1];
    const int*   sample_idx = (const int*)d_in[2];
    float* out = (float*)d_out;
    float* ws  = (float*)d_ws;

    // Layouts:
    //  split: rows [0, 2N*DTOT), accvec [+DTOT), sumsq [+1), counter [+1)
    //  store: rows [0, N*DTOT),  accvec [+DTOT), sumsq [+1), counter [+1)
    const size_t need_split = ((size_t)(2 * NPAIR + 1) * DTOT + 2) * sizeof(float);
    const size_t need_store = ((size_t)(NPAIR + 1) * DTOT + 2) * sizeof(float);

    if (ws_size >= need_split) {
        // Primary: 2 dispatches. accum block 0 zero-inits accvec+counter;
        // fused sum computes the norm in its last block.
        float* accvec = ws + (size_t)2 * NPAIR * DTOT;
        unsigned int* counter = (unsigned int*)(accvec + DTOT + 1);
        sig_accum_kernel<<<2 * NPAIR, 256, 0, stream>>>(original, generated,
                                                        sample_idx, ws, accvec,
                                                        1, 1);
        dim3 g1((DTOT / 2 + 255) / 256, 2 * NPAIR / 32);
        sig_sum_kernel<<<g1, 256, 0, stream>>>(ws, accvec, counter, out,
                                               (int)(g1.x * g1.y));
    } else if (ws_size >= need_store) {
        // Pair-atomic: the two pass-blocks of a pair accumulate into one row.
        float* accvec = ws + (size_t)NPAIR * DTOT;
        unsigned int* counter = (unsigned int*)(accvec + DTOT + 1);
        hipMemsetAsync(ws, 0, need_store, stream);
        sig_accum_kernel<<<2 * NPAIR, 256, 0, stream>>>(original, generated,
                                                        sample_idx, ws, nullptr,
                                                        NPAIR, 0);
        dim3 g1((DTOT / 2 + 255) / 256, NPAIR / 32);
        sig_sum_kernel<<<g1, 256, 0, stream>>>(ws, accvec, counter, out,
                                               (int)(g1.x * g1.y));
    } else {
        int nrep = 1;
        if (ws_size >= ((size_t)64 * DTOT + 2) * sizeof(float)) nrep = 64;
        else if (ws_size >= ((size_t)8 * DTOT + 2) * sizeof(float)) nrep = 8;
        float* sumsq = ws + (size_t)nrep * DTOT;
        unsigned int* counter = (unsigned int*)(sumsq + 1);
        hipMemsetAsync(ws, 0, ((size_t)nrep * DTOT + 2) * sizeof(float), stream);
        sig_accum_kernel<<<2 * NPAIR, 256, 0, stream>>>(original, generated,
                                                        sample_idx, ws, nullptr,
                                                        nrep, 0);
        const int nb2 = (DTOT + 255) / 256;
        sig_reduce_kernel<<<nb2, 256, 0, stream>>>(ws, nrep, sumsq, counter, out, nb2);
    }
}

// Round 8
// 279.219 us; speedup vs baseline: 1.5388x; 1.5388x over previous
//
#include <hip/hip_runtime.h>

// SigWassersteinMetric: depth-4 path signature, C=10, T=256.
//   original: (4096, 256, 10) f32; generated: (1024, 256, 10) f32; sample_idx: (1024,)
//
// ROUND-22: wave-uniform broadcast amortization (128-thread blocks, 2 cell-sets
// per thread) + 3-dispatch structure.
//   - R21: accum-with-block0-init = 185-190us (keep); fused-sum __threadfence
//     per block = +240us DISASTER (revert to fence-free sum + sumsq kernels).
//   - Model (R17 calibrated exactly): LDS 57cyc/wave-step x32 waves/CU = 1824
//     = 193us. 30 of the 57 are wave-uniform reads (va/vb/vc) issued
//     REDUNDANTLY by all 32 waves. This round: 128 threads/block (2 waves),
//     each thread owns cell-sets mbase=2t AND 2t+250 (all 1000 cells covered,
//     disjoint). Per wave-step: 30 uniform + 2x23.4 lane = 77 cyc; 16 waves/CU
//     -> 1229 cyc/CU-step -> ~131us ideal. VALU ~280x4 = 1120 < 1229.
//     This is AMORTIZATION (no pipe migration, no conversion tax).
//   - VGPR watch: ~94 persistent + ~30 working. <=128 -> 16 waves/CU (win);
//     129-168 -> 12 waves/CU + tail (break-even). NO min-waves pin (R15).
//
// Horner-factored Chen step (verified rounds 2/4-13):
//   A2 = S2 + (S1 + v/4) (x) v/3 ;  B2 = S2 + (S1 + v/3) (x) v/2
//   A3 = S3 + A2 (x) v/2 ;  S4' = S4 + A3 (x) v ;  S3' = S3 + B2 (x) v
//   S2' = S2 + (S1 + v/2) (x) v ;  S1 closed-form in epilogue.
#define T_LEN 256
#define C_DIM 10
#define NSTEP 255
#define BSZ   1024
#define NPAIR 1024
#define D1 10
#define D2 100
#define D3 1000
#define DTOT 11110
#define PATH_ELEMS (T_LEN * C_DIM)   // 2560
#define DX_ELEMS (NSTEP * C_DIM)     // 2550
#define DXROW 12                     // padded dx row stride (48 B, 16B-aligned)

typedef float f32x2 __attribute__((ext_vector_type(2)));
typedef float f32x4 __attribute__((ext_vector_type(4)));

// d += bcast(a.lo) * b
#define PK_FMA_B0(d, a, b) \
    asm("v_pk_fma_f32 %0, %1, %2, %0 op_sel:[0,0,0] op_sel_hi:[0,1,1]" \
        : "+v"(d) : "v"(a), "v"(b))
// d += bcast(a.hi) * b
#define PK_FMA_B1(d, a, b) \
    asm("v_pk_fma_f32 %0, %1, %2, %0 op_sel:[1,0,0] op_sel_hi:[1,1,1]" \
        : "+v"(d) : "v"(a), "v"(b))
// d = bcast(a.lo) * b + c
#define PK_FMA_B0N(d, a, b, c) \
    asm("v_pk_fma_f32 %0, %1, %2, %3 op_sel:[0,0,0] op_sel_hi:[0,1,1]" \
        : "=v"(d) : "v"(a), "v"(b), "v"(c))
// d = bcast(a.hi) * b + c
#define PK_FMA_B1N(d, a, b, c) \
    asm("v_pk_fma_f32 %0, %1, %2, %3 op_sel:[1,0,0] op_sel_hi:[1,1,1]" \
        : "=v"(d) : "v"(a), "v"(b), "v"(c))
// d = a * bcast(b.lo) + c   (src1 broadcast)
#define PK_FMA_S1B0N(d, a, b, c) \
    asm("v_pk_fma_f32 %0, %1, %2, %3 op_sel:[0,0,0] op_sel_hi:[1,0,1]" \
        : "=v"(d) : "v"(a), "v"(b), "v"(c))
// d = a * bcast(b.hi) + c
#define PK_FMA_S1B1N(d, a, b, c) \
    asm("v_pk_fma_f32 %0, %1, %2, %3 op_sel:[0,1,0] op_sel_hi:[1,1,1]" \
        : "=v"(d) : "v"(a), "v"(b), "v"(c))
// d += a * bcast(b.lo)
#define PK_FMA_S1B0(d, a, b) \
    asm("v_pk_fma_f32 %0, %1, %2, %0 op_sel:[0,0,0] op_sel_hi:[1,0,1]" \
        : "+v"(d) : "v"(a), "v"(b))
// d += a * bcast(b.hi)
#define PK_FMA_S1B1(d, a, b) \
    asm("v_pk_fma_f32 %0, %1, %2, %0 op_sel:[0,1,0] op_sel_hi:[1,1,1]" \
        : "+v"(d) : "v"(a), "v"(b))
// d = a * 0.5 (both halves)
#define PK_MUL_HALF(d, a) \
    asm("v_pk_mul_f32 %0, %1, 0.5 op_sel:[0,0] op_sel_hi:[1,0]" \
        : "=v"(d) : "v"(a))

__global__ __launch_bounds__(128)
void sig_accum_kernel(
    const float* __restrict__ original,
    const float* __restrict__ generated,
    const int* __restrict__ sample_idx,
    float* __restrict__ ws,
    float* __restrict__ accinit,   // non-null: block 0 zeroes DTOT+2 floats
    int nrep, int store_mode)
{
    const int tid  = threadIdx.x;
    const int bp   = blockIdx.x;         // 0 .. 2*NPAIR-1
    const int b    = bp >> 1;            // pair index
    const int pass = bp & 1;             // 0 = generated (-), 1 = original (+)
    const float sgn = pass ? 1.0f : -1.0f;

    __shared__ __align__(16) float s_dx[NSTEP * DXROW];  // 12240 B

    if (accinit != nullptr && bp == 0) {
        for (int i = tid; i < DTOT + 2; i += 128) accinit[i] = 0.0f;
    }

    const float* path = pass
        ? original + (size_t)sample_idx[b] * PATH_ELEMS
        : generated + (size_t)b * PATH_ELEMS;

    for (int idx = tid; idx < DX_ELEMS; idx += 128) {
        int t = idx / C_DIM, c = idx - t * C_DIM;
        s_dx[t * DXROW + c] = path[idx + C_DIM] - path[idx];
    }
    __syncthreads();

    // Two cell-sets per thread (valid tid<125):
    //   set A: mbase = 2*tid      in [0,250)
    //   set B: mbase = 2*tid+250  in [250,500)
    // Together: 250 mbase values x 4 cells = all 1000 (i,j,k) cells, disjoint.
    const int mA  = 2 * tid;
    const int mB  = 2 * tid + 250;
    const int k0A = mA / 100, ijA = mA - 100 * k0A;
    const int iaA = ijA / 10, j0A = ijA - 10 * iaA;
    const int k0B = mB / 100, ijB = mB - 100 * k0B;
    const int iaB = ijB / 10, j0B = ijB - 10 * iaB;

    float s1A = 0.0f, s1B = 0.0f;
    f32x2 s2A = {0.0f, 0.0f}, s2B = {0.0f, 0.0f};
    f32x2 s3A[2] = {{0.0f, 0.0f}, {0.0f, 0.0f}};
    f32x2 s3B[2] = {{0.0f, 0.0f}, {0.0f, 0.0f}};
    f32x2 accA[4][5], accB[4][5];   // [0]=q0k0 [1]=q1k0 [2]=q0k1 [3]=q1k1
    #pragma unroll
    for (int r = 0; r < 4; ++r)
        #pragma unroll
        for (int i = 0; i < 5; ++i) {
            accA[r][i] = (f32x2){0.0f, 0.0f};
            accB[r][i] = (f32x2){0.0f, 0.0f};
        }

    if (tid < 125) {
        const float* vrow = s_dx;
        #pragma unroll 2
        for (int t = 0; t < NSTEP; ++t, vrow += DXROW) {
            const f32x4 va = *(const f32x4*)(vrow);        // v0..v3 (uniform)
            const f32x4 vb = *(const f32x4*)(vrow + 4);    // v4..v7 (uniform)
            const f32x2 vc = *(const f32x2*)(vrow + 8);    // v8,v9  (uniform)
            const f32x2 vv2[5] = {va.xy, va.zw, vb.xy, vb.zw, vc};

            // ---------------- set A ----------------
            {
                const f32x2 vj = *(const f32x2*)(vrow + j0A);
                const float via = vrow[iaA];
                f32x2 vk; vk.x = vrow[k0A]; vk.y = vrow[k0A + 5];

                const float t3  = fmaf(via, 0.5f, s1A);
                const float t1b = fmaf(via, 0.25f, s1A) * (1.0f / 3.0f);
                const float t2b = fmaf(via, (1.0f / 3.0f), s1A) * 0.5f;
                f32x2 pA_; pA_.x = t1b; pA_.y = t2b;
                f32x2 pT;  pT.x = t3;   pT.y = t3;

                f32x2 vkh;
                PK_MUL_HALF(vkh, vk);

                f32x2 a2, b2;
                PK_FMA_B0N(a2, pA_, vj, s2A);
                PK_FMA_B1N(b2, pA_, vj, s2A);
                PK_FMA_B0(s2A, pT, vj);

                f32x2 a3x, a3y;
                PK_FMA_S1B0N(a3x, a2, vkh, s3A[0]);
                PK_FMA_S1B1N(a3y, a2, vkh, s3A[1]);
                PK_FMA_S1B0(s3A[0], b2, vk);
                PK_FMA_S1B1(s3A[1], b2, vk);

                #pragma unroll
                for (int i = 0; i < 5; ++i) {
                    PK_FMA_B0(accA[0][i], a3x, vv2[i]);
                    PK_FMA_B1(accA[1][i], a3x, vv2[i]);
                    PK_FMA_B0(accA[2][i], a3y, vv2[i]);
                    PK_FMA_B1(accA[3][i], a3y, vv2[i]);
                }
                s1A += via;
            }
            // ---------------- set B ----------------
            {
                const f32x2 vj = *(const f32x2*)(vrow + j0B);
                const float via = vrow[iaB];
                f32x2 vk; vk.x = vrow[k0B]; vk.y = vrow[k0B + 5];

                const float t3  = fmaf(via, 0.5f, s1B);
                const float t1b = fmaf(via, 0.25f, s1B) * (1.0f / 3.0f);
                const float t2b = fmaf(via, (1.0f / 3.0f), s1B) * 0.5f;
                f32x2 pA_; pA_.x = t1b; pA_.y = t2b;
                f32x2 pT;  pT.x = t3;   pT.y = t3;

                f32x2 vkh;
                PK_MUL_HALF(vkh, vk);

                f32x2 a2, b2;
                PK_FMA_B0N(a2, pA_, vj, s2B);
                PK_FMA_B1N(b2, pA_, vj, s2B);
                PK_FMA_B0(s2B, pT, vj);

                f32x2 a3x, a3y;
                PK_FMA_S1B0N(a3x, a2, vkh, s3B[0]);
                PK_FMA_S1B1N(a3y, a2, vkh, s3B[1]);
                PK_FMA_S1B0(s3B[0], b2, vk);
                PK_FMA_S1B1(s3B[1], b2, vk);

                #pragma unroll
                for (int i = 0; i < 5; ++i) {
                    PK_FMA_B0(accB[0][i], a3x, vv2[i]);
                    PK_FMA_B1(accB[1][i], a3x, vv2[i]);
                    PK_FMA_B0(accB[2][i], a3y, vv2[i]);
                    PK_FMA_B1(accB[3][i], a3y, vv2[i]);
                }
                s1B += via;
            }
        }
    }

    // ---- Epilogue: signed single-path row ----
    if (store_mode) {
        float* row = ws + (size_t)bp * DTOT;
        if (tid < D1)
            row[tid] = sgn * (path[(T_LEN - 1) * C_DIM + tid] - path[tid]);
        if (tid < 50) {       // set A, k0A == 0 threads own ij pair 2*tid
            row[D1 + ijA]     = sgn * s2A[0];
            row[D1 + ijA + 1] = sgn * s2A[1];
        }
        if (tid < 125) {
            #pragma unroll
            for (int ch = 0; ch < 2; ++ch) {          // ch=0 -> k0, ch=1 -> k0+5
                const int kkA = k0A + 5 * ch;
                #pragma unroll
                for (int q = 0; q < 2; ++q) {
                    const int idx3 = (ijA + q) * 10 + kkA;
                    row[D1 + D2 + idx3] = sgn * s3A[ch][q];
                    float* p4 = row + D1 + D2 + D3 + (size_t)idx3 * 10;
                    #pragma unroll
                    for (int i = 0; i < 5; ++i)
                        *(f32x2*)&p4[2 * i] = sgn * accA[ch * 2 + q][i];
                }
            }
            #pragma unroll
            for (int ch = 0; ch < 2; ++ch) {
                const int kkB = k0B + 5 * ch;
                #pragma unroll
                for (int q = 0; q < 2; ++q) {
                    const int idx3 = (ijB + q) * 10 + kkB;
                    row[D1 + D2 + idx3] = sgn * s3B[ch][q];
                    float* p4 = row + D1 + D2 + D3 + (size_t)idx3 * 10;
                    #pragma unroll
                    for (int i = 0; i < 5; ++i)
                        *(f32x2*)&p4[2 * i] = sgn * accB[ch * 2 + q][i];
                }
            }
        }
    } else {
        float* base = ws + (size_t)(b % nrep) * DTOT;
        if (tid < D1)
            atomicAdd(&base[tid],
                      sgn * (path[(T_LEN - 1) * C_DIM + tid] - path[tid]));
        if (tid < 50) {
            atomicAdd(&base[D1 + ijA],     sgn * s2A[0]);
            atomicAdd(&base[D1 + ijA + 1], sgn * s2A[1]);
        }
        if (tid < 125) {
            #pragma unroll
            for (int ch = 0; ch < 2; ++ch) {
                const int kkA = k0A + 5 * ch;
                #pragma unroll
                for (int q = 0; q < 2; ++q) {
                    const int idx3 = (ijA + q) * 10 + kkA;
                    atomicAdd(&base[D1 + D2 + idx3], sgn * s3A[ch][q]);
                    #pragma unroll
                    for (int l = 0; l < 10; ++l)
                        atomicAdd(&base[D1 + D2 + D3 + idx3 * 10 + l],
                                  sgn * accA[ch * 2 + q][l >> 1][l & 1]);
                }
            }
            #pragma unroll
            for (int ch = 0; ch < 2; ++ch) {
                const int kkB = k0B + 5 * ch;
                #pragma unroll
                for (int q = 0; q < 2; ++q) {
                    const int idx3 = (ijB + q) * 10 + kkB;
                    atomicAdd(&base[D1 + D2 + idx3], sgn * s3B[ch][q]);
                    #pragma unroll
                    for (int l = 0; l < 10; ++l)
                        atomicAdd(&base[D1 + D2 + D3 + idx3 * 10 + l],
                                  sgn * accB[ch * 2 + q][l >> 1][l & 1]);
                }
            }
        }
    }
}

// Stage 1: block sums 32 rows for a float2 d-tile (coalesced), atomically
// accumulates into accvec[DTOT]. Grid: (ceil(5555/256), nrows/32). NO fences.
__global__ __launch_bounds__(256) void sig_sum_kernel(
    const float* __restrict__ ws, float* __restrict__ accvec)
{
    const int d2 = blockIdx.x * 256 + threadIdx.x;   // DTOT/2 = 5555
    if (d2 >= DTOT / 2) return;
    const float* p = ws + (size_t)(blockIdx.y * 32) * DTOT + 2 * d2;
    float sx = 0.0f, sy = 0.0f;
    #pragma unroll
    for (int r = 0; r < 32; ++r) {
        const float2 v = *(const float2*)(p + (size_t)r * DTOT);
        sx += v.x; sy += v.y;
    }
    atomicAdd(&accvec[2 * d2], sx);
    atomicAdd(&accvec[2 * d2 + 1], sy);
}

// Stage 2: sum of squares -> sumsq; last block writes the norm.
__global__ __launch_bounds__(256) void sig_sumsq_kernel(
    const float* __restrict__ accvec, float* __restrict__ sumsq,
    unsigned int* __restrict__ counter, float* __restrict__ out, int nblocks)
{
    const int d = blockIdx.x * 256 + threadIdx.x;
    float s = 0.0f;
    if (d < DTOT) { float v = accvec[d]; s = v * v; }
    for (int off = 32; off > 0; off >>= 1) s += __shfl_down(s, off, 64);
    __shared__ float red[4];
    __shared__ unsigned int lastflag;
    if ((threadIdx.x & 63) == 0) red[threadIdx.x >> 6] = s;
    __syncthreads();
    if (threadIdx.x == 0) {
        atomicAdd(sumsq, red[0] + red[1] + red[2] + red[3]);
        __threadfence();
        lastflag = (atomicAdd(counter, 1u) == (unsigned int)(nblocks - 1));
    }
    __syncthreads();
    if (threadIdx.x == 0 && lastflag) {
        __threadfence();
        out[0] = sqrtf(*(volatile float*)sumsq) * (1.0f / (float)BSZ);
    }
}

// Fallback reduce for small-ws atomic-replica modes.
__global__ __launch_bounds__(256) void sig_reduce_kernel(
    const float* __restrict__ ws, int nrows, float* __restrict__ sumsq,
    unsigned int* __restrict__ counter, float* __restrict__ out, int nblocks)
{
    const int d = blockIdx.x * 256 + threadIdx.x;
    float s = 0.0f;
    if (d < DTOT) {
        for (int r = 0; r < nrows; ++r) s += ws[(size_t)r * DTOT + d];
        s = s * s;
    }
    for (int off = 32; off > 0; off >>= 1) s += __shfl_down(s, off, 64);
    __shared__ float red[4];
    __shared__ unsigned int lastflag;
    if ((threadIdx.x & 63) == 0) red[threadIdx.x >> 6] = s;
    __syncthreads();
    if (threadIdx.x == 0) {
        atomicAdd(sumsq, red[0] + red[1] + red[2] + red[3]);
        __threadfence();
        lastflag = (atomicAdd(counter, 1u) == (unsigned int)(nblocks - 1));
    }
    __syncthreads();
    if (threadIdx.x == 0 && lastflag) {
        __threadfence();
        out[0] = sqrtf(*(volatile float*)sumsq) * (1.0f / (float)BSZ);
    }
}

extern "C" void kernel_launch(void* const* d_in, const int* in_sizes, int n_in,
                              void* d_out, int out_size, void* d_ws, size_t ws_size,
                              hipStream_t stream) {
    const float* original   = (const float*)d_in[0];
    const float* generated  = (const float*)d_in[1];
    const int*   sample_idx = (const int*)d_in[2];
    float* out = (float*)d_out;
    float* ws  = (float*)d_ws;

    // Layouts:
    //  split: rows [0, 2N*DTOT), accvec [+DTOT), sumsq [+1), counter [+1)
    //  store: rows [0, N*DTOT),  accvec [+DTOT), sumsq [+1), counter [+1)
    const size_t need_split = ((size_t)(2 * NPAIR + 1) * DTOT + 2) * sizeof(float);
    const size_t need_store = ((size_t)(NPAIR + 1) * DTOT + 2) * sizeof(float);

    if (ws_size >= need_split) {
        // Primary: 3 dispatches. accum block 0 zero-inits accvec+sumsq+counter.
        float* accvec = ws + (size_t)2 * NPAIR * DTOT;
        float* sumsq  = accvec + DTOT;
        unsigned int* counter = (unsigned int*)(sumsq + 1);
        sig_accum_kernel<<<2 * NPAIR, 128, 0, stream>>>(original, generated,
                                                        sample_idx, ws, accvec,
                                                        1, 1);
        dim3 g1((DTOT / 2 + 255) / 256, 2 * NPAIR / 32);
        sig_sum_kernel<<<g1, 256, 0, stream>>>(ws, accvec);
        const int nb2 = (DTOT + 255) / 256;
        sig_sumsq_kernel<<<nb2, 256, 0, stream>>>(accvec, sumsq, counter, out, nb2);
    } else if (ws_size >= need_store) {
        // Pair-atomic: the two pass-blocks of a pair accumulate into one row.
        float* accvec = ws + (size_t)NPAIR * DTOT;
        float* sumsq  = accvec + DTOT;
        unsigned int* counter = (unsigned int*)(sumsq + 1);
        hipMemsetAsync(ws, 0, need_store, stream);
        sig_accum_kernel<<<2 * NPAIR, 128, 0, stream>>>(original, generated,
                                                        sample_idx, ws, nullptr,
                                                        NPAIR, 0);
        dim3 g1((DTOT / 2 + 255) / 256, NPAIR / 32);
        sig_sum_kernel<<<g1, 256, 0, stream>>>(ws, accvec);
        const int nb2 = (DTOT + 255) / 256;
        sig_sumsq_kernel<<<nb2, 256, 0, stream>>>(accvec, sumsq, counter, out, nb2);
    } else {
        int nrep = 1;
        if (ws_size >= ((size_t)64 * DTOT + 2) * sizeof(float)) nrep = 64;
        else if (ws_size >= ((size_t)8 * DTOT + 2) * sizeof(float)) nrep = 8;
        float* sumsq = ws + (size_t)nrep * DTOT;
        unsigned int* counter = (unsigned int*)(sumsq + 1);
        hipMemsetAsync(ws, 0, ((size_t)nrep * DTOT + 2) * sizeof(float), stream);
        sig_accum_kernel<<<2 * NPAIR, 128, 0, stream>>>(original, generated,
                                                        sample_idx, ws, nullptr,
                                                        nrep, 0);
        const int nb2 = (DTOT + 255) / 256;
        sig_reduce_kernel<<<nb2, 256, 0, stream>>>(ws, nrep, sumsq, counter, out, nb2);
    }
}